// Round 18
// baseline (275.515 us; speedup 1.0000x reference)
//
#include <hip/hip_runtime.h>
#include <stdint.h>

// Problem constants
constexpr int NCELLS = 802816;             // 16384 * 7 * 7
constexpr int TILE   = 64;                 // cells per wave-tile (1 cell/lane)
constexpr int NTILES = NCELLS / TILE;      // 12544 (exact)
constexpr int NWAVES = 1280;               // 5 LDS-limited blocks/CU * 256 CU
constexpr int TBYTES = TILE * 30 * 4;      // 7680 B per tensor per tile

__global__ void zero_out_kernel(float* out) {
    if (threadIdx.x < 5) out[threadIdx.x] = 0.0f;
}

typedef const uint32_t __attribute__((address_space(1)))* gptr_t;
typedef uint32_t       __attribute__((address_space(3)))* lptr_t;

// Round-17 fix of the r13 design. r16 FAILED correctness (absmax 6e6,
// finite and float-valued => channel-scrambled LDS, not junk): size=12
// DMA lane-stride is UNVERIFIED on gfx950 (guide verifies stride==size
// only for 4B [m03] and 16B [m97]). Restage with verified widths only:
// per tensor 7680 B = 7 x dwordx4 (stride 16) + 2 x dword (stride 4)
// = 9 instrs, 18 per tile; counted wait becomes vmcnt(18).
// Also: tail-drain vmcnt(0) after the loop (r16 ended with 20 DMA writes
// in flight -> can corrupt a reallocated LDS slot across launches).
// Pipeline unchanged: double-buffered LDS-DMA, issue tile k+1's loads,
// s_waitcnt vmcnt(18) waits only for tile k's older loads; 5 blocks/CU,
// grid = 1280 = exact resident capacity.
__global__ __launch_bounds__(64, 1) void yolo_loss_kernel(
    const float* __restrict__ pred,
    const float* __restrict__ tgt,
    float* __restrict__ out)
{
    __shared__ float smem[2][2 * TBYTES / 4];   // 2 buffers x (pred|tgt) = 30720 B
    const int lane = threadIdx.x;               // 0..63, 1 wave per block

    float acc0 = 0.f, acc1 = 0.f, acc2 = 0.f, acc3 = 0.f, acc4 = 0.f;

    char* const bufA = (char*)&smem[0][0];
    char* const bufB = (char*)&smem[1][0];

    // Stage one tile (both tensors) into DST via LDS-DMA, verified widths:
    //  - 7 x dwordx4: instr j writes lane i at DST + j*1024 + i*16  [m97]
    //  - 2 x dword:   instr j writes lane i at DST + 7168 + j*256 + i*4 [m03]
    // Global source mirrors the same linear offsets -> LDS = identity copy.
#define STAGE(DST, TI)                                                        \
    {                                                                         \
        const char* gsp = (const char*)pred + (size_t)(TI) * TBYTES;          \
        const char* gst = (const char*)tgt  + (size_t)(TI) * TBYTES;          \
        _Pragma("unroll")                                                     \
        for (int j = 0; j < 7; ++j) {                                         \
            __builtin_amdgcn_global_load_lds(                                 \
                (gptr_t)(gsp + j * 1024 + lane * 16),                         \
                (lptr_t)(void*)((DST) + j * 1024), 16, 0, 0);                 \
            __builtin_amdgcn_global_load_lds(                                 \
                (gptr_t)(gst + j * 1024 + lane * 16),                         \
                (lptr_t)(void*)((DST) + TBYTES + j * 1024), 16, 0, 0);        \
        }                                                                     \
        _Pragma("unroll")                                                     \
        for (int j = 0; j < 2; ++j) {                                         \
            __builtin_amdgcn_global_load_lds(                                 \
                (gptr_t)(gsp + 7168 + j * 256 + lane * 4),                    \
                (lptr_t)(void*)((DST) + 7168 + j * 256), 4, 0, 0);            \
            __builtin_amdgcn_global_load_lds(                                 \
                (gptr_t)(gst + 7168 + j * 256 + lane * 4),                    \
                (lptr_t)(void*)((DST) + TBYTES + 7168 + j * 256), 4, 0, 0);   \
        }                                                                     \
    }

    int tile = blockIdx.x;                      // wave-private tile stream
    char* cur = bufA;
    char* nxt = bufB;
    STAGE(cur, tile);                           // prologue: fill buffer A (18 loads)

    for (; tile < NTILES; tile += NWAVES) {
        int ntile = tile + NWAVES;
        if (ntile >= NTILES) ntile = tile;      // clamp: harmless re-stage keeps
        STAGE(nxt, ntile);                      // the vmcnt count fixed at 18
        // Wait for the 18 OLDER loads (current tile); the 18 just issued for
        // the next tile remain in flight under this iteration's compute.
        asm volatile("s_waitcnt vmcnt(18)" ::: "memory");
        __builtin_amdgcn_sched_barrier(0);      // block ds_read hoist above wait

        // Each lane owns one cell: 15 x ds_read_b64, static indices only
        // (round-2 lesson: runtime indexing -> scratch).
        const float2* myp = (const float2*)(cur)          + lane * 15;
        const float2* myt = (const float2*)(cur + TBYTES) + lane * 15;
        float p[30], t[30];
        #pragma unroll
        for (int j = 0; j < 15; ++j) {
            float2 a = myp[j]; p[2*j] = a.x; p[2*j+1] = a.y;
            float2 b = myt[j]; t[2*j] = b.x; t[2*j+1] = b.y;
        }

        const float tconf = t[4];               // exactly 0.0 or 1.0
        const float m  = (tconf > 0.0f) ? 1.0f : 0.0f;
        const float nm = 1.0f - m;

        const float t0x1 = t[0], t0y1 = t[1], t0x2 = t[2], t0y2 = t[3];
        const float a2 = (t0x2 - t0x1) * (t0y2 - t0y1);

        float iou0, iou1;
        {
            const float ltx = fmaxf(p[0], t0x1), lty = fmaxf(p[1], t0y1);
            const float rbx = fminf(p[2], t0x2), rby = fminf(p[3], t0y2);
            const float wx = fmaxf(rbx - ltx, 0.0f), wy = fmaxf(rby - lty, 0.0f);
            const float inter = wx * wy;
            const float a1 = (p[2] - p[0]) * (p[3] - p[1]);
            iou0 = inter / (a1 + a2 - inter);
        }
        {
            const float ltx = fmaxf(p[5], t0x1), lty = fmaxf(p[6], t0y1);
            const float rbx = fminf(p[7], t0x2), rby = fminf(p[8], t0y2);
            const float wx = fmaxf(rbx - ltx, 0.0f), wy = fmaxf(rby - lty, 0.0f);
            const float inter = wx * wy;
            const float a1 = (p[7] - p[5]) * (p[8] - p[6]);
            iou1 = inter / (a1 + a2 - inter);
        }

        const float max_iou = fmaxf(iou0, iou1);
        const bool b1 = iou1 > iou0;            // first index wins ties

        const float rpx = b1 ? p[5] : p[0];
        const float rpy = b1 ? p[6] : p[1];
        const float rpw = b1 ? p[7] : p[2];
        const float rph = b1 ? p[8] : p[3];
        const float rpc = b1 ? p[9] : p[4];
        const float rtx = b1 ? t[5] : t[0];
        const float rty = b1 ? t[6] : t[1];
        const float rtw = b1 ? t[7] : t[2];
        const float rth = b1 ? t[8] : t[3];

        {   // xy
            const float dx = rpx - rtx, dy = rpy - rty;
            acc0 += m * (dx*dx + dy*dy);
        }
        {   // wh (inputs in (0.05,0.95) so sqrt args > 0)
            const float dw = sqrtf(rpw) - sqrtf(rtw);
            const float dh = sqrtf(rph) - sqrtf(rth);
            acc1 += m * (dw*dw + dh*dh);
        }
        {   // obj
            const float d = rpc - max_iou;
            acc2 += m * d * d;
        }
        {   // noobj (channels 4, 9)
            const float d0 = p[4] - t[4];
            const float d1 = p[9] - t[9];
            acc3 += nm * (d0*d0 + d1*d1);
        }
        {   // class (channels 10..29)
            float cl = 0.f;
            #pragma unroll
            for (int k = 10; k < 30; ++k) {
                const float d = p[k] - t[k];
                cl += d * d;
            }
            acc4 += m * cl;
        }

        { char* tmp = cur; cur = nxt; nxt = tmp; }   // swap buffers
    }
#undef STAGE

    // Drain the tail tile's in-flight DMA before the wave can retire:
    // late LDS writes into a reallocated slot corrupt a later launch.
    asm volatile("s_waitcnt vmcnt(0)" ::: "memory");

    // ---- reduction: wave (64 lanes) -> global atomics (1 wave/block) ----
    float acc[5] = {acc0, acc1, acc2, acc3, acc4};
    #pragma unroll
    for (int i = 0; i < 5; ++i) {
        float v = acc[i];
        #pragma unroll
        for (int o = 32; o > 0; o >>= 1)
            v += __shfl_down(v, o, 64);
        if (lane == 0) atomicAdd(out + i, v);
    }
}

extern "C" void kernel_launch(void* const* d_in, const int* in_sizes, int n_in,
                              void* d_out, int out_size, void* d_ws, size_t ws_size,
                              hipStream_t stream) {
    const float* pred = (const float*)d_in[0];
    const float* tgt  = (const float*)d_in[1];
    float* out = (float*)d_out;

    hipLaunchKernelGGL(zero_out_kernel, dim3(1), dim3(64), 0, stream, out);

    // 1280 blocks x 64 threads = 1280 waves = 5 blocks/CU (LDS-bound),
    // exactly the resident capacity. Each wave pipelines ~10 tiles.
    hipLaunchKernelGGL(yolo_loss_kernel, dim3(NWAVES), dim3(64), 0, stream,
                       pred, tgt, out);
}